// Round 8
// baseline (209.624 us; speedup 1.0000x reference)
//
#include <hip/hip_runtime.h>
#include <cstdint>

using u16 = unsigned short;
typedef __bf16 bf16x8 __attribute__((ext_vector_type(8)));
typedef __bf16 bf16x4 __attribute__((ext_vector_type(4)));
typedef __bf16 bf16x2 __attribute__((ext_vector_type(2)));
typedef float f32x4 __attribute__((ext_vector_type(4)));

#define MFMA16(a, b, c) __builtin_amdgcn_mfma_f32_16x16x32_bf16((a), (b), (c), 0, 0, 0)

__device__ __forceinline__ u16 f2bf(float f) {
  union { float f; uint32_t u; } c; c.f = f;
  uint32_t u = c.u;
  u += 0x7fffu + ((u >> 16) & 1u);   // RNE
  return (u16)(u >> 16);
}

#if __has_builtin(__builtin_amdgcn_global_load_lds)
#define GLOAD_LDS16(g, l)                                                      \
  __builtin_amdgcn_global_load_lds(                                            \
      (__attribute__((address_space(1))) void*)(g),                            \
      (__attribute__((address_space(3))) void*)(l), 16, 0, 0)
#else
#define GLOAD_LDS16(g, l) do { *(uint4*)(l) = *(const uint4*)(g); } while (0)
#endif

// In-register P^T fragment build.
// lo covers k_local 0..15, hi k_local 16..31 (C-layout quad*4+r rows);
// output B-fragment: lane(quad,l16) holds P[k_local = quad*8 + j][q=l16].
__device__ __forceinline__ bf16x8 ptrans(const f32x4 lo, const f32x4 hi) {
  union W { bf16x2 h; uint32_t u; } wl0, wl1, wh0, wh1;
  wl0.h[0] = (__bf16)lo[0]; wl0.h[1] = (__bf16)lo[1];
  wl1.h[0] = (__bf16)lo[2]; wl1.h[1] = (__bf16)lo[3];
  wh0.h[0] = (__bf16)hi[0]; wh0.h[1] = (__bf16)hi[1];
  wh1.h[0] = (__bf16)hi[2]; wh1.h[1] = (__bf16)hi[3];
  uint32_t a0 = wl0.u, b0 = wh0.u, a1 = wl1.u, b1 = wh1.u;
  asm("v_permlane32_swap_b32 %0, %1" : "+v"(a0), "+v"(b0));
  asm("v_permlane16_swap_b32 %0, %1" : "+v"(a0), "+v"(b0));
  asm("v_permlane32_swap_b32 %0, %1" : "+v"(a1), "+v"(b1));
  asm("v_permlane16_swap_b32 %0, %1" : "+v"(a1), "+v"(b1));
  union R { uint32_t u[4]; bf16x8 v; } r;
  r.u[0] = a0; r.u[1] = a1; r.u[2] = b0; r.u[3] = b1;
  return r.v;
}

// ---------------- fused prep: x->bf16, w_qkv^T->bf16, w_out^T->bf16 --------
__global__ __launch_bounds__(256) void prep(
    const float* __restrict__ x, const float* __restrict__ w_qkv,
    const float* __restrict__ w_out, u16* __restrict__ xb,
    u16* __restrict__ wqT, u16* __restrict__ woT) {
  const int bid = blockIdx.x, tid = threadIdx.x;
  if (bid < 4096) {
    int i = (bid * 256 + tid) * 4;
    float4 v = *(const float4*)&x[i];
    ushort4 p;
    p.x = f2bf(v.x); p.y = f2bf(v.y); p.z = f2bf(v.z); p.w = f2bf(v.w);
    *(ushort4*)&xb[i] = p;
    return;
  }
  __shared__ float tile[32][33];
  int t = bid - 4096;
  const float* in;
  u16* outp;
  int C, bx, by;
  if (t < 3072) { in = w_qkv; outp = wqT; C = 3072; bx = (t % 96) * 32; by = (t / 96) * 32; }
  else { t -= 3072; in = w_out; outp = woT; C = 1024; bx = (t % 32) * 32; by = (t / 32) * 32; }
  const int tx = tid & 31, ty = tid >> 5;
#pragma unroll
  for (int r2 = 0; r2 < 4; ++r2)
    tile[ty + r2 * 8][tx] = in[(size_t)(by + ty + r2 * 8) * C + bx + tx];
  __syncthreads();
#pragma unroll
  for (int r2 = 0; r2 < 4; ++r2)
    outp[(size_t)(bx + ty + r2 * 8) * 1024 + by + tx] = f2bf(tile[tx][ty + r2 * 8]);
}

// ---------------- GEMM 128x128 + XCD-affine remap: QKV scatter -------------
// v16: bijective remap of the 768 blocks so each XCD owns a 512-row A-slice
// (1 MB, L2-resident) and its 4 m-blocks per n-panel reuse the B-panel from
// L2 (mi fastest). Correctness-neutral (m0/n0 only).
__global__ __launch_bounds__(256, 3) void gemm_qkv(
    const u16* __restrict__ A, const u16* __restrict__ Bt,
    const float* __restrict__ bias,
    u16* __restrict__ qb, u16* __restrict__ kb, u16* __restrict__ vb,
    int M, int N, int K) {
  __shared__ u16 As[128 * 32];
  __shared__ u16 Bs[128 * 32];
  const int tid = threadIdx.x;
  const int lin = blockIdx.y * 32 + blockIdx.x;   // [0,768)
  const int xcd = lin & 7;
  const int r = lin >> 3;                          // [0,96)
  const int mi = r & 3, nj = r >> 2;               // 4 m-blocks x 24 n-panels
  const int m0 = (xcd * 4 + mi) * 128;
  const int n0 = nj * 128;
  const int lane = tid & 63, w = tid >> 6;
  const int quad = lane >> 4, l16 = lane & 15;
  const int wr = w >> 1, wc = w & 1;

  f32x4 acc[4][4] = {};

  const int r0 = tid >> 2, p0 = tid & 3;
  const int r1 = r0 + 64;
  const int c8 = p0 ^ ((r0 >> 1) & 3);
  const u16* ga0 = A + (size_t)(m0 + r0) * K + c8 * 8;
  const u16* ga1 = A + (size_t)(m0 + r1) * K + c8 * 8;
  const u16* gb0 = Bt + (size_t)(n0 + r0) * K + c8 * 8;
  const u16* gb1 = Bt + (size_t)(n0 + r1) * K + c8 * 8;
  u16* la0 = &As[tid * 8];
  u16* la1 = &As[(tid + 256) * 8];
  u16* lb0 = &Bs[tid * 8];
  u16* lb1 = &Bs[(tid + 256) * 8];

  int aoff[4], boff[4];
#pragma unroll
  for (int i = 0; i < 4; ++i) {
    int ra = wr * 64 + i * 16 + l16;
    aoff[i] = (ra * 4 + (quad ^ ((ra >> 1) & 3))) * 8;
    int rb = wc * 64 + i * 16 + l16;
    boff[i] = (rb * 4 + (quad ^ ((rb >> 1) & 3))) * 8;
  }

  const int nIter = K >> 5;
  for (int kt = 0; kt < nIter; ++kt) {
    __syncthreads();
    const int kk = kt << 5;
    GLOAD_LDS16(ga0 + kk, la0);
    GLOAD_LDS16(ga1 + kk, la1);
    GLOAD_LDS16(gb0 + kk, lb0);
    GLOAD_LDS16(gb1 + kk, lb1);
    __syncthreads();
    bf16x8 af[4], bfr[4];
#pragma unroll
    for (int i = 0; i < 4; ++i) af[i] = *(const bf16x8*)&As[aoff[i]];
#pragma unroll
    for (int j = 0; j < 4; ++j) bfr[j] = *(const bf16x8*)&Bs[boff[j]];
#pragma unroll
    for (int i = 0; i < 4; ++i)
#pragma unroll
      for (int j = 0; j < 4; ++j)
        acc[i][j] = MFMA16(af[i], bfr[j], acc[i][j]);
  }

  const int S = 2048, NH = 16;
#pragma unroll
  for (int i = 0; i < 4; ++i) {
    const int mb = m0 + wr * 64 + i * 16 + quad * 4;
#pragma unroll
    for (int j = 0; j < 4; ++j) {
      const int n = n0 + wc * 64 + j * 16 + l16;
      const float bv = bias[n];
      const int which = n >> 10;      // 0:Q 1:K 2:V (uniform per block)
      const int hn = n & 1023;
      const int h = hn >> 6, d = hn & 63;
      const int b = mb >> 11, s = mb & 2047;
      const int bh = b * NH + h;
      if (which == 2) {
        ushort4 pk;
        pk.x = f2bf(acc[i][j][0] + bv);
        pk.y = f2bf(acc[i][j][1] + bv);
        pk.z = f2bf(acc[i][j][2] + bv);
        pk.w = f2bf(acc[i][j][3] + bv);
        *(ushort4*)&vb[((size_t)bh * 64 + d) * S + s] = pk;  // V transposed
      } else {
        // Q pre-scaled by HD^-0.5 * log2(e): scores land in exp2 domain
        const float sc = (which == 0) ? 0.18033688f : 1.0f;
        u16* dst = (which == 0) ? qb : kb;
#pragma unroll
        for (int r2 = 0; r2 < 4; ++r2)
          dst[((size_t)bh * S + s + r2) * 64 + d] = f2bf((acc[i][j][r2] + bv) * sc);
      }
    }
  }
}

// ---------------- GEMM 64x128: out = A @ Bt^T + bias (fp32 out) ----------
__global__ __launch_bounds__(256, 2) void gemm_out(
    const u16* __restrict__ A, const u16* __restrict__ Bt,
    const float* __restrict__ bias, float* __restrict__ outf,
    int M, int N, int K) {
  __shared__ u16 As[64 * 32];
  __shared__ u16 Bs[128 * 32];
  const int tid = threadIdx.x;
  const int m0 = blockIdx.x * 64;
  const int n0 = blockIdx.y * 128;
  const int lane = tid & 63, w = tid >> 6;
  const int quad = lane >> 4, l16 = lane & 15;
  const int wr = w >> 1, wc = w & 1;

  f32x4 acc[2][4] = {};

  const int r0 = tid >> 2, p0 = tid & 3;
  const int c8 = p0 ^ ((r0 >> 1) & 3);
  const u16* ga0 = A + (size_t)(m0 + r0) * K + c8 * 8;
  const u16* gb0 = Bt + (size_t)(n0 + r0) * K + c8 * 8;
  const u16* gb1 = Bt + (size_t)(n0 + r0 + 64) * K + c8 * 8;
  u16* la0 = &As[tid * 8];
  u16* lb0 = &Bs[tid * 8];
  u16* lb1 = &Bs[(tid + 256) * 8];

  int aoff[2], boff[4];
#pragma unroll
  for (int i = 0; i < 2; ++i) {
    int ra = wr * 32 + i * 16 + l16;
    aoff[i] = (ra * 4 + (quad ^ ((ra >> 1) & 3))) * 8;
  }
#pragma unroll
  for (int j = 0; j < 4; ++j) {
    int rb = wc * 64 + j * 16 + l16;
    boff[j] = (rb * 4 + (quad ^ ((rb >> 1) & 3))) * 8;
  }

  const int nIter = K >> 5;
  for (int kt = 0; kt < nIter; ++kt) {
    __syncthreads();
    const int kk = kt << 5;
    GLOAD_LDS16(ga0 + kk, la0);
    GLOAD_LDS16(gb0 + kk, lb0);
    GLOAD_LDS16(gb1 + kk, lb1);
    __syncthreads();
    bf16x8 af[2], bfr[4];
#pragma unroll
    for (int i = 0; i < 2; ++i) af[i] = *(const bf16x8*)&As[aoff[i]];
#pragma unroll
    for (int j = 0; j < 4; ++j) bfr[j] = *(const bf16x8*)&Bs[boff[j]];
#pragma unroll
    for (int i = 0; i < 2; ++i)
#pragma unroll
      for (int j = 0; j < 4; ++j)
        acc[i][j] = MFMA16(af[i], bfr[j], acc[i][j]);
  }

#pragma unroll
  for (int i = 0; i < 2; ++i) {
    const int mb = m0 + wr * 32 + i * 16 + quad * 4;
#pragma unroll
    for (int j = 0; j < 4; ++j) {
      const int n = n0 + wc * 64 + j * 16 + l16;
      const float bv = bias[n];
#pragma unroll
      for (int r = 0; r < 4; ++r)
        outf[(size_t)(mb + r) * N + n] = acc[i][j][r] + bv;
    }
  }
}

// ---------------- flash attention v16: K from L2, 4 blocks/CU --------------
// v15 post-mortem: halving LDS reads was NEUTRAL -> LDS port not the limit.
// MfmaUtil pinned at 33% across 6 structures; invariant = 2 big lockstep-ish
// units/SIMD traversing QK->exp2->ptrans->PV together (matrix pipe idles in
// the VALU phases). v16 creates 4 INDEPENDENT phase-domains per SIMD:
//  - K LDS staging dropped; A-fragments read directly from global/L2. The
//    address is algebraically what staging+swizzle produced: logical granule
//    quad of row kt*128+wk*64+ct*16+l16 = kbase + row*64 + quad*8 (+32).
//    Pattern: 128 B row-stride, 16 B/lane -> 16x64B segments/load (2x
//    transaction inflation, L2-hit; NOT R3's 4 KB-stride V disaster).
//  - Blocks shrink to 64 q-rows, 4 waves (wq x wk as v15); grid 32x32=1024
//    = 4 blocks/CU exactly (LDS 32 KB/block, launch_bounds(256,4)).
//  - V staging/layout/read + ptrans + rowsum + wk-reduce: verified v15 code.
__global__ __launch_bounds__(256, 4) void attn_fa(
    const u16* __restrict__ qg, const u16* __restrict__ kg,
    const u16* __restrict__ vg, u16* __restrict__ o) {
  const int S = 2048;
  // bijective XCD-affine remap: 128 chunks/XCD; bh = xcd*4 + (chunk&3),
  // qblk = chunk>>2 in [0,32). Per-XCD K/V footprint 2 MB -> L2-resident.
  const int lin = blockIdx.x;
  const int xcd = lin & 7, chunk = lin >> 3;
  const int bh = xcd * 4 + (chunk & 3);
  const int qblk = chunk >> 2;
  const int b = bh >> 4, h = bh & 15;
  const int tid = threadIdx.x, w = tid >> 6, lane = tid & 63;
  const int quad = lane >> 4, l16 = lane & 15;
  const int wq = w >> 1, wk = w & 1;

  __shared__ u16 Vs[2][8192];   // [2 hh][64 d-rows][8 granules], ^(row&7)

  const int q0w = qblk * 64 + wq * 32;
  // Q B-frags qf[qt][dh]: lane holds Q[q=q0w+qt*16+l16][d=dh*32+quad*8+j]
  bf16x8 qf[2][2];
#pragma unroll
  for (int qt = 0; qt < 2; ++qt)
#pragma unroll
    for (int dh = 0; dh < 2; ++dh)
      qf[qt][dh] = *(const bf16x8*)(qg + ((size_t)bh * S + q0w + qt * 16 + l16) * 64 +
                                    dh * 32 + quad * 8);

  f32x4 accO[4][2] = {};   // [dt][qt]
  f32x4 accL[2] = {};      // [qt] rowsums (ones-MFMA)

  bf16x8 ones;
#pragma unroll
  for (int i = 0; i < 8; ++i) ones[i] = (__bf16)1.0f;

  const u16* kbase = kg + (size_t)bh * S * 64;
  const u16* vbase = vg + (size_t)bh * 64 * S;

  // direct K A-frag base: row (wk*64 + l16), granule quad; +ct*1024 walks ct,
  // +kt*8192 walks tiles, +32 is the second granule set (d 32..63).
  const u16* kFrag = kbase + (size_t)(wk * 64 + l16) * 64 + quad * 8;

  // V staging (4 insts/tile, tid-based; verbatim v13/v15 verified pattern)
  const int vd0 = tid >> 3, vg0 = tid & 7;
  const u16* vSrc = vbase + (size_t)vd0 * S + (vg0 ^ (vd0 & 7)) * 8;

  const int kgA = (quad ^ (l16 & 7)) * 8;
  const int kgB = ((quad + 4) ^ (l16 & 7)) * 8;

#define STAGE_V(KT, NB)                                                       \
  {                                                                           \
    _Pragma("unroll")                                                         \
    for (int seg = 0; seg < 4; ++seg)                                         \
      GLOAD_LDS16(vSrc + (size_t)(seg & 1) * 32 * S + (KT) * 128 +            \
                      (seg >> 1) * 64,                                        \
                  &Vs[NB][(seg * 256 + tid) * 8]);                            \
  }

  STAGE_V(0, 0);

  for (int kt = 0; kt < 16; ++kt) {
    const int cur = kt & 1;
    __syncthreads();            // V glds(kt) landed; buf[cur^1] reads done
    if (kt + 1 < 16) STAGE_V(kt + 1, cur ^ 1);

    // ---- K A-frags straight from L2 (8 global_load_dwordx4) ----
    const u16* kT = kFrag + (size_t)kt * 8192;
    bf16x8 kfA[4], kfB[4];
#pragma unroll
    for (int ct = 0; ct < 4; ++ct) {
      kfA[ct] = *(const bf16x8*)(kT + ct * 1024);
      kfB[ct] = *(const bf16x8*)(kT + ct * 1024 + 32);
    }

    // ---- S^T = K Q^T (16 MFMA) ----
    f32x4 s[4][2] = {};
    __builtin_amdgcn_s_setprio(1);
#pragma unroll
    for (int ct = 0; ct < 4; ++ct)
#pragma unroll
      for (int qt = 0; qt < 2; ++qt) {
        s[ct][qt] = MFMA16(kfA[ct], qf[qt][0], s[ct][qt]);
        s[ct][qt] = MFMA16(kfB[ct], qf[qt][1], s[ct][qt]);
      }
    __builtin_amdgcn_s_setprio(0);

    // ---- P = exp2(s) ----
#pragma unroll
    for (int ct = 0; ct < 4; ++ct)
#pragma unroll
      for (int qt = 0; qt < 2; ++qt)
#pragma unroll
        for (int r = 0; r < 4; ++r)
          s[ct][qt][r] = __builtin_amdgcn_exp2f(s[ct][qt][r]);

    // ---- P^T fragments in-register ----
    bf16x8 pf[2][2];
#pragma unroll
    for (int qt = 0; qt < 2; ++qt) {
      pf[0][qt] = ptrans(s[0][qt], s[1][qt]);
      pf[1][qt] = ptrans(s[2][qt], s[3][qt]);
    }

    // ---- V frags for this wave's key-half (8 ds_read_b128, hh = wk) ----
    const u16* Vc = Vs[cur];
    bf16x8 vfA[4], vfB[4];
#pragma unroll
    for (int dt = 0; dt < 4; ++dt) {
      const int rb = wk * 4096 + (dt * 16 + l16) * 64;
      vfA[dt] = *(const bf16x8*)&Vc[rb + kgA];
      vfB[dt] = *(const bf16x8*)&Vc[rb + kgB];
    }

    // ---- rowsums + O^T += V^T P^T (20 MFMA) ----
    __builtin_amdgcn_s_setprio(1);
#pragma unroll
    for (int qt = 0; qt < 2; ++qt) {
      accL[qt] = MFMA16(ones, pf[0][qt], accL[qt]);
      accL[qt] = MFMA16(ones, pf[1][qt], accL[qt]);
    }
#pragma unroll
    for (int dt = 0; dt < 4; ++dt)
#pragma unroll
      for (int qt = 0; qt < 2; ++qt) {
        accO[dt][qt] = MFMA16(vfA[dt], pf[0][qt], accO[dt][qt]);
        accO[dt][qt] = MFMA16(vfB[dt], pf[1][qt], accO[dt][qt]);
      }
    __builtin_amdgcn_s_setprio(0);
  }
#undef STAGE_V

  // ---- cross-wk reduce through LDS (reuse Vs; one-time) ----
  __syncthreads();                      // all tile-15 V reads complete
  float* redO = (float*)&Vs[0][0];      // 16 slots x 256 f32 = 16 KB
  float* redL = (float*)&Vs[1][0];      // 64 f32
  if (wk == 1) {
#pragma unroll
    for (int dt = 0; dt < 4; ++dt)
#pragma unroll
      for (int qt = 0; qt < 2; ++qt)
        *(f32x4*)&redO[((wq * 8 + dt * 2 + qt) << 8) + lane * 4] = accO[dt][qt];
    if (quad == 0) {
#pragma unroll
      for (int qt = 0; qt < 2; ++qt)
        redL[wq * 32 + qt * 16 + l16] = accL[qt][0];
    }
  }
  __syncthreads();
  if (wk == 0) {
#pragma unroll
    for (int dt = 0; dt < 4; ++dt)
#pragma unroll
      for (int qt = 0; qt < 2; ++qt)
        accO[dt][qt] += *(const f32x4*)&redO[((wq * 8 + dt * 2 + qt) << 8) + lane * 4];
#pragma unroll
    for (int qt = 0; qt < 2; ++qt) {
      const float inv = 1.f / (accL[qt][0] + redL[wq * 32 + qt * 16 + l16]);
      const int qrow = q0w + qt * 16 + l16;
#pragma unroll
      for (int dt = 0; dt < 4; ++dt) {
        ushort4 pk;
        pk.x = f2bf(accO[dt][qt][0] * inv);
        pk.y = f2bf(accO[dt][qt][1] * inv);
        pk.z = f2bf(accO[dt][qt][2] * inv);
        pk.w = f2bf(accO[dt][qt][3] * inv);
        *(ushort4*)&o[(size_t)(b * S + qrow) * 1024 + h * 64 + dt * 16 + quad * 4] = pk;
      }
    }
  }
}

// ---------------- launch ----------------

extern "C" void kernel_launch(void* const* d_in, const int* in_sizes, int n_in,
                              void* d_out, int out_size, void* d_ws, size_t ws_size,
                              hipStream_t stream) {
  const float* x = (const float*)d_in[0];
  const float* w_qkv = (const float*)d_in[1];
  const float* b_qkv = (const float*)d_in[2];
  const float* w_out = (const float*)d_in[3];
  const float* b_out = (const float*)d_in[4];
  float* out = (float*)d_out;

  u16* xb = (u16*)d_ws;                 // [4096,1024]
  u16* wqT = xb + 4096 * 1024;          // [3072,1024]
  u16* woT = wqT + 3072 * 1024;         // [1024,1024]
  u16* qb = woT + 1024 * 1024;          // [32,2048,64] (pre-scaled)
  u16* kb = qb + 4194304;               // [32,2048,64]
  u16* vb = kb + 4194304;               // [32,64,2048]
  u16* ao = vb + 4194304;               // [4096,1024]

  prep<<<8192, 256, 0, stream>>>(x, w_qkv, w_out, xb, wqT, woT);
  gemm_qkv<<<dim3(32, 24), 256, 0, stream>>>(xb, wqT, b_qkv, qb, kb, vb,
                                             4096, 3072, 1024);
  attn_fa<<<1024, 256, 0, stream>>>(qb, kb, vb, ao);
  gemm_out<<<dim3(64, 8), 256, 0, stream>>>(ao, woT, b_out, out,
                                            4096, 1024, 1024);
}

// Round 9
// 176.895 us; speedup vs baseline: 1.1850x; 1.1850x over previous
//
#include <hip/hip_runtime.h>
#include <cstdint>

using u16 = unsigned short;
typedef __bf16 bf16x8 __attribute__((ext_vector_type(8)));
typedef __bf16 bf16x4 __attribute__((ext_vector_type(4)));
typedef __bf16 bf16x2 __attribute__((ext_vector_type(2)));
typedef float f32x4 __attribute__((ext_vector_type(4)));

#define MFMA16(a, b, c) __builtin_amdgcn_mfma_f32_16x16x32_bf16((a), (b), (c), 0, 0, 0)

__device__ __forceinline__ u16 f2bf(float f) {
  union { float f; uint32_t u; } c; c.f = f;
  uint32_t u = c.u;
  u += 0x7fffu + ((u >> 16) & 1u);   // RNE
  return (u16)(u >> 16);
}

#if __has_builtin(__builtin_amdgcn_global_load_lds)
#define GLOAD_LDS16(g, l)                                                      \
  __builtin_amdgcn_global_load_lds(                                            \
      (__attribute__((address_space(1))) void*)(g),                            \
      (__attribute__((address_space(3))) void*)(l), 16, 0, 0)
#else
#define GLOAD_LDS16(g, l) do { *(uint4*)(l) = *(const uint4*)(g); } while (0)
#endif

// In-register P^T fragment build.
// lo covers k_local 0..15, hi k_local 16..31 (C-layout quad*4+r rows);
// output B-fragment: lane(quad,l16) holds P[k_local = quad*8 + j][q=l16].
__device__ __forceinline__ bf16x8 ptrans(const f32x4 lo, const f32x4 hi) {
  union W { bf16x2 h; uint32_t u; } wl0, wl1, wh0, wh1;
  wl0.h[0] = (__bf16)lo[0]; wl0.h[1] = (__bf16)lo[1];
  wl1.h[0] = (__bf16)lo[2]; wl1.h[1] = (__bf16)lo[3];
  wh0.h[0] = (__bf16)hi[0]; wh0.h[1] = (__bf16)hi[1];
  wh1.h[0] = (__bf16)hi[2]; wh1.h[1] = (__bf16)hi[3];
  uint32_t a0 = wl0.u, b0 = wh0.u, a1 = wl1.u, b1 = wh1.u;
  asm("v_permlane32_swap_b32 %0, %1" : "+v"(a0), "+v"(b0));
  asm("v_permlane16_swap_b32 %0, %1" : "+v"(a0), "+v"(b0));
  asm("v_permlane32_swap_b32 %0, %1" : "+v"(a1), "+v"(b1));
  asm("v_permlane16_swap_b32 %0, %1" : "+v"(a1), "+v"(b1));
  union R { uint32_t u[4]; bf16x8 v; } r;
  r.u[0] = a0; r.u[1] = a1; r.u[2] = b0; r.u[3] = b1;
  return r.v;
}

// ---------------- prep (weights only now): w_qkv^T->bf16, w_out^T->bf16 ----
// x->bf16 pass FUSED into gemm_qkv (R8): grid 8192 -> 4096, -24 MB traffic.
__global__ __launch_bounds__(256) void prep(
    const float* __restrict__ w_qkv, const float* __restrict__ w_out,
    u16* __restrict__ wqT, u16* __restrict__ woT) {
  const int tid = threadIdx.x;
  __shared__ float tile[32][33];
  int t = blockIdx.x;
  const float* in;
  u16* outp;
  int C, bx, by;
  if (t < 3072) { in = w_qkv; outp = wqT; C = 3072; bx = (t % 96) * 32; by = (t / 96) * 32; }
  else { t -= 3072; in = w_out; outp = woT; C = 1024; bx = (t % 32) * 32; by = (t / 32) * 32; }
  const int tx = tid & 31, ty = tid >> 5;
#pragma unroll
  for (int r2 = 0; r2 < 4; ++r2)
    tile[ty + r2 * 8][tx] = in[(size_t)(by + ty + r2 * 8) * C + bx + tx];
  __syncthreads();
#pragma unroll
  for (int r2 = 0; r2 < 4; ++r2)
    outp[(size_t)(bx + ty + r2 * 8) * 1024 + by + tx] = f2bf(tile[tx][ty + r2 * 8]);
}

// ---------------- GEMM 128x128 + XCD remap + fused f32 A (QKV scatter) -----
// R8: A staged directly from x (f32) -- 16 KB f32 LDS tile, 4 glds/K-step,
// granule(16B)-XOR swizzle; frag read = 2x f32x4 + in-reg cvt to bf16
// (v_cvt RNE == prep's f2bf, values identical). Bank math: bank depends only
// on XORed granule (8 values) -> 16 lanes / 8 groups = 2-way = free (m136).
// LDS 16+8=24 KB -> still 3 blocks/CU. XCD remap (v16) kept.
__global__ __launch_bounds__(256, 3) void gemm_qkv(
    const float* __restrict__ X, const u16* __restrict__ Bt,
    const float* __restrict__ bias,
    u16* __restrict__ qb, u16* __restrict__ kb, u16* __restrict__ vb,
    int M, int N, int K) {
  __shared__ float As4[128 * 32];   // [128 rows][8 granules of 4 f32]
  __shared__ u16 Bs[128 * 32];
  const int tid = threadIdx.x;
  const int lin = blockIdx.y * 32 + blockIdx.x;   // [0,768)
  const int xcd = lin & 7;
  const int rr = lin >> 3;                         // [0,96)
  const int mi = rr & 3, nj = rr >> 2;             // 4 m-blocks x 24 n-panels
  const int m0 = (xcd * 4 + mi) * 128;
  const int n0 = nj * 128;
  const int lane = tid & 63, w = tid >> 6;
  const int quad = lane >> 4, l16 = lane & 15;
  const int wr = w >> 1, wc = w & 1;

  f32x4 acc[4][4] = {};

  // A staging: inst j covers rows j*32 + (tid>>3); phys granule tid&7 holds
  // logical granule (tid&7)^(row&7); row&7 == (tid>>3)&7 for all j.
  const int tr = tid >> 3, tp = tid & 7;
  const int ag = tp ^ (tr & 7);
  const float* gaX = X + (size_t)(m0 + tr) * K + ag * 4;

  // B staging (verbatim): 2 insts, rows tid>>2 and +64, granule XOR over 4.
  const int r0 = tid >> 2, p0 = tid & 3;
  const int c8 = p0 ^ ((r0 >> 1) & 3);
  const u16* gb0 = Bt + (size_t)(n0 + r0) * K + c8 * 8;
  const u16* gb1 = Bt + (size_t)(n0 + r0 + 64) * K + c8 * 8;
  u16* lb0 = &Bs[tid * 8];
  u16* lb1 = &Bs[(tid + 256) * 8];

  int aoffA[4], boff[4];
#pragma unroll
  for (int i = 0; i < 4; ++i) {
    int ra = wr * 64 + i * 16 + l16;
    aoffA[i] = (ra * 8 + ((quad * 2) ^ (ra & 7))) * 4;   // f32 index of granule
    int rb = wc * 64 + i * 16 + l16;
    boff[i] = (rb * 4 + (quad ^ ((rb >> 1) & 3))) * 8;
  }

  const int nIter = K >> 5;
  for (int kt = 0; kt < nIter; ++kt) {
    __syncthreads();
    const int kk = kt << 5;
#pragma unroll
    for (int j = 0; j < 4; ++j)
      GLOAD_LDS16(gaX + (size_t)j * 32 * K + kk, &As4[(j * 256 + tid) * 4]);
    GLOAD_LDS16(gb0 + kk, lb0);
    GLOAD_LDS16(gb1 + kk, lb1);
    __syncthreads();
    bf16x8 af[4], bfr[4];
#pragma unroll
    for (int i = 0; i < 4; ++i) {
      f32x4 a0 = *(const f32x4*)&As4[aoffA[i]];
      f32x4 a1 = *(const f32x4*)&As4[aoffA[i] ^ 4];   // granule^1 = +-4 f32
      af[i][0] = (__bf16)a0[0]; af[i][1] = (__bf16)a0[1];
      af[i][2] = (__bf16)a0[2]; af[i][3] = (__bf16)a0[3];
      af[i][4] = (__bf16)a1[0]; af[i][5] = (__bf16)a1[1];
      af[i][6] = (__bf16)a1[2]; af[i][7] = (__bf16)a1[3];
    }
#pragma unroll
    for (int j = 0; j < 4; ++j) bfr[j] = *(const bf16x8*)&Bs[boff[j]];
#pragma unroll
    for (int i = 0; i < 4; ++i)
#pragma unroll
      for (int j = 0; j < 4; ++j)
        acc[i][j] = MFMA16(af[i], bfr[j], acc[i][j]);
  }

  const int S = 2048, NH = 16;
#pragma unroll
  for (int i = 0; i < 4; ++i) {
    const int mb = m0 + wr * 64 + i * 16 + quad * 4;
#pragma unroll
    for (int j = 0; j < 4; ++j) {
      const int n = n0 + wc * 64 + j * 16 + l16;
      const float bv = bias[n];
      const int which = n >> 10;      // 0:Q 1:K 2:V (uniform per block)
      const int hn = n & 1023;
      const int h = hn >> 6, d = hn & 63;
      const int b = mb >> 11, s = mb & 2047;
      const int bh = b * NH + h;
      if (which == 2) {
        ushort4 pk;
        pk.x = f2bf(acc[i][j][0] + bv);
        pk.y = f2bf(acc[i][j][1] + bv);
        pk.z = f2bf(acc[i][j][2] + bv);
        pk.w = f2bf(acc[i][j][3] + bv);
        *(ushort4*)&vb[((size_t)bh * 64 + d) * S + s] = pk;  // V transposed
      } else {
        // Q pre-scaled by HD^-0.5 * log2(e): scores land in exp2 domain
        const float sc = (which == 0) ? 0.18033688f : 1.0f;
        u16* dst = (which == 0) ? qb : kb;
#pragma unroll
        for (int r2 = 0; r2 < 4; ++r2)
          dst[((size_t)bh * S + s + r2) * 64 + d] = f2bf((acc[i][j][r2] + bv) * sc);
      }
    }
  }
}

// ---------------- GEMM 64x128: out = A @ Bt^T + bias (fp32 out) ----------
__global__ __launch_bounds__(256, 2) void gemm_out(
    const u16* __restrict__ A, const u16* __restrict__ Bt,
    const float* __restrict__ bias, float* __restrict__ outf,
    int M, int N, int K) {
  __shared__ u16 As[64 * 32];
  __shared__ u16 Bs[128 * 32];
  const int tid = threadIdx.x;
  const int m0 = blockIdx.x * 64;
  const int n0 = blockIdx.y * 128;
  const int lane = tid & 63, w = tid >> 6;
  const int quad = lane >> 4, l16 = lane & 15;
  const int wr = w >> 1, wc = w & 1;

  f32x4 acc[2][4] = {};

  const int r0 = tid >> 2, p0 = tid & 3;
  const int c8 = p0 ^ ((r0 >> 1) & 3);
  const u16* ga0 = A + (size_t)(m0 + r0) * K + c8 * 8;
  const u16* gb0 = Bt + (size_t)(n0 + r0) * K + c8 * 8;
  const u16* gb1 = Bt + (size_t)(n0 + r0 + 64) * K + c8 * 8;
  u16* la0 = &As[tid * 8];
  u16* lb0 = &Bs[tid * 8];
  u16* lb1 = &Bs[(tid + 256) * 8];

  int aoff[2], boff[4];
#pragma unroll
  for (int i = 0; i < 2; ++i) {
    int ra = wr * 32 + i * 16 + l16;
    aoff[i] = (ra * 4 + (quad ^ ((ra >> 1) & 3))) * 8;
  }
#pragma unroll
  for (int j = 0; j < 4; ++j) {
    int rb = wc * 64 + j * 16 + l16;
    boff[j] = (rb * 4 + (quad ^ ((rb >> 1) & 3))) * 8;
  }

  const int nIter = K >> 5;
  for (int kt = 0; kt < nIter; ++kt) {
    __syncthreads();
    const int kk = kt << 5;
    GLOAD_LDS16(ga0 + kk, la0);
    GLOAD_LDS16(gb0 + kk, lb0);
    GLOAD_LDS16(gb1 + kk, lb1);
    __syncthreads();
    bf16x8 af[2], bfr[4];
#pragma unroll
    for (int i = 0; i < 2; ++i) af[i] = *(const bf16x8*)&As[aoff[i]];
#pragma unroll
    for (int j = 0; j < 4; ++j) bfr[j] = *(const bf16x8*)&Bs[boff[j]];
#pragma unroll
    for (int i = 0; i < 2; ++i)
#pragma unroll
      for (int j = 0; j < 4; ++j)
        acc[i][j] = MFMA16(af[i], bfr[j], acc[i][j]);
  }

#pragma unroll
  for (int i = 0; i < 2; ++i) {
    const int mb = m0 + wr * 32 + i * 16 + quad * 4;
#pragma unroll
    for (int j = 0; j < 4; ++j) {
      const int n = n0 + wc * 64 + j * 16 + l16;
      const float bv = bias[n];
#pragma unroll
      for (int r = 0; r < 4; ++r)
        outf[(size_t)(mb + r) * N + n] = acc[i][j][r] + bv;
    }
  }
}

// ---------------- flash attention v13 (RESTORED: best measured 43.9 us) ----
// R7 post-mortem: K-from-global (v16) halved MfmaUtil (18%) despite 2x
// occupancy -> fragment feeds must come from LDS. v13 = 128-key dbuf tiles,
// K+V both LDS (128B-row conflict-free layouts), in-register ptrans,
// XCD-affine remap, bulk frag reads. Attention plateau for this structure.
__global__ __launch_bounds__(256, 2) void attn_fa(
    const u16* __restrict__ qg, const u16* __restrict__ kg,
    const u16* __restrict__ vg, u16* __restrict__ o) {
  const int S = 2048;
  const int lin = blockIdx.x;
  const int xcd = lin & 7, chunk = lin >> 3;
  const int bh = xcd * 4 + (chunk & 3);
  const int qblk = chunk >> 2;
  const int b = bh >> 4, h = bh & 15;
  const int tid = threadIdx.x, w = tid >> 6, lane = tid & 63;
  const int quad = lane >> 4, l16 = lane & 15;

  __shared__ u16 Ks[2][8192];   // [128 key-rows][8 granules], ^(row&7) swizzle
  __shared__ u16 Vs[2][8192];   // [2 hh][64 d-rows][8 granules], ^(row&7)

  const int q0 = qblk * 128 + w * 32;
  const u16* qp = qg + ((size_t)bh * S + q0 + l16) * 64 + quad * 8;
  const bf16x8 qf00 = *(const bf16x8*)qp;
  const bf16x8 qf01 = *(const bf16x8*)(qp + 32);
  const bf16x8 qf10 = *(const bf16x8*)(qp + 1024);
  const bf16x8 qf11 = *(const bf16x8*)(qp + 1024 + 32);

  f32x4 accO0[4] = {}, accO1[4] = {};
  f32x4 accL0 = {}, accL1 = {};

  bf16x8 ones;
#pragma unroll
  for (int i = 0; i < 8; ++i) ones[i] = (__bf16)1.0f;

  const u16* kbase = kg + (size_t)bh * S * 64;
  const u16* vbase = vg + (size_t)bh * 64 * S;

  const int sr0 = tid >> 3, sp0 = tid & 7;
  const int c8s = sp0 ^ (sr0 & 7);
  const u16* kSrc = kbase + (size_t)sr0 * 64 + c8s * 8;
  const u16* vSrc = vbase + (size_t)sr0 * S + c8s * 8;

  const int kgA = (quad ^ (l16 & 7)) * 8;
  const int kgB = ((quad + 4) ^ (l16 & 7)) * 8;

#define STAGE_KV(KT, NB)                                                      \
  {                                                                           \
    _Pragma("unroll")                                                         \
    for (int seg = 0; seg < 4; ++seg) {                                       \
      GLOAD_LDS16(kSrc + (size_t)((KT) * 128 + seg * 32) * 64,                \
                  &Ks[NB][(seg * 256 + tid) * 8]);                            \
      GLOAD_LDS16(vSrc + (size_t)(seg & 1) * 32 * S + (KT) * 128 +            \
                      (seg >> 1) * 64,                                        \
                  &Vs[NB][(seg * 256 + tid) * 8]);                            \
    }                                                                         \
  }

  // preload tile 0 into buffer 0
  STAGE_KV(0, 0);

  for (int kt = 0; kt < 16; ++kt) {
    const int cur = kt & 1;
    __syncthreads();  // glds(kt) landed; buf[cur^1] reads of kt-1 complete
    const u16* Kc = Ks[cur];
    const u16* Vc = Vs[cur];

    // ---- ALL fragment reads upfront (32 x ds_read_b128) ----
    bf16x8 kf00[4], kf01[4], kf10[4], kf11[4];
    bf16x8 vf00[4], vf01[4], vf10[4], vf11[4];
#pragma unroll
    for (int ct = 0; ct < 4; ++ct) {
      const int rb0 = (ct * 16 + l16) * 64;
      const int rb1 = (64 + ct * 16 + l16) * 64;
      kf00[ct] = *(const bf16x8*)&Kc[rb0 + kgA];
      kf01[ct] = *(const bf16x8*)&Kc[rb0 + kgB];
      kf10[ct] = *(const bf16x8*)&Kc[rb1 + kgA];
      kf11[ct] = *(const bf16x8*)&Kc[rb1 + kgB];
      vf00[ct] = *(const bf16x8*)&Vc[rb0 + kgA];
      vf01[ct] = *(const bf16x8*)&Vc[rb0 + kgB];
      vf10[ct] = *(const bf16x8*)&Vc[4096 + rb0 + kgA];
      vf11[ct] = *(const bf16x8*)&Vc[4096 + rb0 + kgB];
    }

    // ---- prefetch next tile ----
    if (kt + 1 < 16) STAGE_KV(kt + 1, cur ^ 1);

    // ---- S^T = K Q^T, both halves ----
    f32x4 s0[4] = {}, s1[4] = {}, t0[4] = {}, t1[4] = {};
    __builtin_amdgcn_s_setprio(1);
#pragma unroll
    for (int ct = 0; ct < 4; ++ct) {
      s0[ct] = MFMA16(kf00[ct], qf00, s0[ct]);
      s0[ct] = MFMA16(kf01[ct], qf01, s0[ct]);
      s1[ct] = MFMA16(kf00[ct], qf10, s1[ct]);
      s1[ct] = MFMA16(kf01[ct], qf11, s1[ct]);
      t0[ct] = MFMA16(kf10[ct], qf00, t0[ct]);
      t0[ct] = MFMA16(kf11[ct], qf01, t0[ct]);
      t1[ct] = MFMA16(kf10[ct], qf10, t1[ct]);
      t1[ct] = MFMA16(kf11[ct], qf11, t1[ct]);
    }
    __builtin_amdgcn_s_setprio(0);

    // ---- P = exp2(s) ----
#pragma unroll
    for (int ct = 0; ct < 4; ++ct)
#pragma unroll
      for (int r = 0; r < 4; ++r) {
        s0[ct][r] = __builtin_amdgcn_exp2f(s0[ct][r]);
        s1[ct][r] = __builtin_amdgcn_exp2f(s1[ct][r]);
        t0[ct][r] = __builtin_amdgcn_exp2f(t0[ct][r]);
        t1[ct][r] = __builtin_amdgcn_exp2f(t1[ct][r]);
      }

    // ---- P^T fragments in-register ----
    bf16x8 pf00 = ptrans(s0[0], s0[1]);
    bf16x8 pf01 = ptrans(s0[2], s0[3]);
    bf16x8 pf10 = ptrans(s1[0], s1[1]);
    bf16x8 pf11 = ptrans(s1[2], s1[3]);
    bf16x8 pg00 = ptrans(t0[0], t0[1]);
    bf16x8 pg01 = ptrans(t0[2], t0[3]);
    bf16x8 pg10 = ptrans(t1[0], t1[1]);
    bf16x8 pg11 = ptrans(t1[2], t1[3]);

    // ---- row sums + O^T += V^T P^T, both halves ----
    __builtin_amdgcn_s_setprio(1);
    accL0 = MFMA16(ones, pf00, accL0);
    accL0 = MFMA16(ones, pf01, accL0);
    accL1 = MFMA16(ones, pf10, accL1);
    accL1 = MFMA16(ones, pf11, accL1);
    accL0 = MFMA16(ones, pg00, accL0);
    accL0 = MFMA16(ones, pg01, accL0);
    accL1 = MFMA16(ones, pg10, accL1);
    accL1 = MFMA16(ones, pg11, accL1);
#pragma unroll
    for (int ct = 0; ct < 4; ++ct) {
      accO0[ct] = MFMA16(vf00[ct], pf00, accO0[ct]);
      accO0[ct] = MFMA16(vf01[ct], pf01, accO0[ct]);
      accO1[ct] = MFMA16(vf00[ct], pf10, accO1[ct]);
      accO1[ct] = MFMA16(vf01[ct], pf11, accO1[ct]);
      accO0[ct] = MFMA16(vf10[ct], pg00, accO0[ct]);
      accO0[ct] = MFMA16(vf11[ct], pg01, accO0[ct]);
      accO1[ct] = MFMA16(vf10[ct], pg10, accO1[ct]);
      accO1[ct] = MFMA16(vf11[ct], pg11, accO1[ct]);
    }
    __builtin_amdgcn_s_setprio(0);
  }
#undef STAGE_KV

  const float inv0 = 1.f / accL0[0], inv1 = 1.f / accL1[0];

  const int s0r = q0 + l16, s1r = q0 + 16 + l16;
#pragma unroll
  for (int ct = 0; ct < 4; ++ct) {
    ushort4 pk;
    pk.x = f2bf(accO0[ct][0] * inv0);
    pk.y = f2bf(accO0[ct][1] * inv0);
    pk.z = f2bf(accO0[ct][2] * inv0);
    pk.w = f2bf(accO0[ct][3] * inv0);
    *(ushort4*)&o[(size_t)(b * S + s0r) * 1024 + h * 64 + ct * 16 + quad * 4] = pk;
    pk.x = f2bf(accO1[ct][0] * inv1);
    pk.y = f2bf(accO1[ct][1] * inv1);
    pk.z = f2bf(accO1[ct][2] * inv1);
    pk.w = f2bf(accO1[ct][3] * inv1);
    *(ushort4*)&o[(size_t)(b * S + s1r) * 1024 + h * 64 + ct * 16 + quad * 4] = pk;
  }
}

// ---------------- launch ----------------

extern "C" void kernel_launch(void* const* d_in, const int* in_sizes, int n_in,
                              void* d_out, int out_size, void* d_ws, size_t ws_size,
                              hipStream_t stream) {
  const float* x = (const float*)d_in[0];
  const float* w_qkv = (const float*)d_in[1];
  const float* b_qkv = (const float*)d_in[2];
  const float* w_out = (const float*)d_in[3];
  const float* b_out = (const float*)d_in[4];
  float* out = (float*)d_out;

  u16* xb = (u16*)d_ws;                 // [4096,1024] (unused after R8 fusion)
  u16* wqT = xb + 4096 * 1024;          // [3072,1024]
  u16* woT = wqT + 3072 * 1024;         // [1024,1024]
  u16* qb = woT + 1024 * 1024;          // [32,2048,64] (pre-scaled)
  u16* kb = qb + 4194304;               // [32,2048,64]
  u16* vb = kb + 4194304;               // [32,64,2048]
  u16* ao = vb + 4194304;               // [4096,1024]

  prep<<<4096, 256, 0, stream>>>(w_qkv, w_out, wqT, woT);
  gemm_qkv<<<dim3(32, 24), 256, 0, stream>>>(x, wqT, b_qkv, qb, kb, vb,
                                             4096, 3072, 1024);
  attn_fa<<<512, 256, 0, stream>>>(qb, kb, vb, ao);
  gemm_out<<<dim3(64, 8), 256, 0, stream>>>(ao, woT, b_out, out,
                                            4096, 1024, 1024);
}

// Round 10
// 175.681 us; speedup vs baseline: 1.1932x; 1.0069x over previous
//
#include <hip/hip_runtime.h>
#include <cstdint>

using u16 = unsigned short;
typedef __bf16 bf16x8 __attribute__((ext_vector_type(8)));
typedef __bf16 bf16x4 __attribute__((ext_vector_type(4)));
typedef __bf16 bf16x2 __attribute__((ext_vector_type(2)));
typedef float f32x4 __attribute__((ext_vector_type(4)));

#define MFMA16(a, b, c) __builtin_amdgcn_mfma_f32_16x16x32_bf16((a), (b), (c), 0, 0, 0)

__device__ __forceinline__ u16 f2bf(float f) {
  union { float f; uint32_t u; } c; c.f = f;
  uint32_t u = c.u;
  u += 0x7fffu + ((u >> 16) & 1u);   // RNE
  return (u16)(u >> 16);
}

#if __has_builtin(__builtin_amdgcn_global_load_lds)
#define GLOAD_LDS16(g, l)                                                      \
  __builtin_amdgcn_global_load_lds(                                            \
      (__attribute__((address_space(1))) void*)(g),                            \
      (__attribute__((address_space(3))) void*)(l), 16, 0, 0)
#else
#define GLOAD_LDS16(g, l) do { *(uint4*)(l) = *(const uint4*)(g); } while (0)
#endif

// In-register P^T fragment build.
// lo covers k_local 0..15, hi k_local 16..31 (C-layout quad*4+r rows);
// output B-fragment: lane(quad,l16) holds P[k_local = quad*8 + j][q=l16].
__device__ __forceinline__ bf16x8 ptrans(const f32x4 lo, const f32x4 hi) {
  union W { bf16x2 h; uint32_t u; } wl0, wl1, wh0, wh1;
  wl0.h[0] = (__bf16)lo[0]; wl0.h[1] = (__bf16)lo[1];
  wl1.h[0] = (__bf16)lo[2]; wl1.h[1] = (__bf16)lo[3];
  wh0.h[0] = (__bf16)hi[0]; wh0.h[1] = (__bf16)hi[1];
  wh1.h[0] = (__bf16)hi[2]; wh1.h[1] = (__bf16)hi[3];
  uint32_t a0 = wl0.u, b0 = wh0.u, a1 = wl1.u, b1 = wh1.u;
  asm("v_permlane32_swap_b32 %0, %1" : "+v"(a0), "+v"(b0));
  asm("v_permlane16_swap_b32 %0, %1" : "+v"(a0), "+v"(b0));
  asm("v_permlane32_swap_b32 %0, %1" : "+v"(a1), "+v"(b1));
  asm("v_permlane16_swap_b32 %0, %1" : "+v"(a1), "+v"(b1));
  union R { uint32_t u[4]; bf16x8 v; } r;
  r.u[0] = a0; r.u[1] = a1; r.u[2] = b0; r.u[3] = b1;
  return r.v;
}

// ---------------- fused prep: x->bf16, w_qkv^T->bf16, w_out^T->bf16 --------
// R9: R8's fusion of x->bf16 into gemm_qkv REVERTED (128B-f32-row LDS tile
// is a structural 8-way bank conflict -- 3.1M measured -- and f32 A doubles
// the x24-reuse L2 traffic). Conversion belongs in this single-pass kernel.
__global__ __launch_bounds__(256) void prep(
    const float* __restrict__ x, const float* __restrict__ w_qkv,
    const float* __restrict__ w_out, u16* __restrict__ xb,
    u16* __restrict__ wqT, u16* __restrict__ woT) {
  const int bid = blockIdx.x, tid = threadIdx.x;
  if (bid < 4096) {
    int i = (bid * 256 + tid) * 4;
    float4 v = *(const float4*)&x[i];
    ushort4 p;
    p.x = f2bf(v.x); p.y = f2bf(v.y); p.z = f2bf(v.z); p.w = f2bf(v.w);
    *(ushort4*)&xb[i] = p;
    return;
  }
  __shared__ float tile[32][33];
  int t = bid - 4096;
  const float* in;
  u16* outp;
  int C, bx, by;
  if (t < 3072) { in = w_qkv; outp = wqT; C = 3072; bx = (t % 96) * 32; by = (t / 96) * 32; }
  else { t -= 3072; in = w_out; outp = woT; C = 1024; bx = (t % 32) * 32; by = (t / 32) * 32; }
  const int tx = tid & 31, ty = tid >> 5;
#pragma unroll
  for (int r2 = 0; r2 < 4; ++r2)
    tile[ty + r2 * 8][tx] = in[(size_t)(by + ty + r2 * 8) * C + bx + tx];
  __syncthreads();
#pragma unroll
  for (int r2 = 0; r2 < 4; ++r2)
    outp[(size_t)(bx + ty + r2 * 8) * 1024 + by + tx] = f2bf(tile[tx][ty + r2 * 8]);
}

// ---------------- GEMM 128x128 (R10, best measured): QKV scatter -----------
__global__ __launch_bounds__(256, 3) void gemm_qkv(
    const u16* __restrict__ A, const u16* __restrict__ Bt,
    const float* __restrict__ bias,
    u16* __restrict__ qb, u16* __restrict__ kb, u16* __restrict__ vb,
    int M, int N, int K) {
  __shared__ u16 As[128 * 32];
  __shared__ u16 Bs[128 * 32];
  const int tid = threadIdx.x;
  const int m0 = blockIdx.x * 128;
  const int n0 = blockIdx.y * 128;
  const int lane = tid & 63, w = tid >> 6;
  const int quad = lane >> 4, l16 = lane & 15;
  const int wr = w >> 1, wc = w & 1;

  f32x4 acc[4][4] = {};

  const int r0 = tid >> 2, p0 = tid & 3;
  const int r1 = r0 + 64;
  const int c8 = p0 ^ ((r0 >> 1) & 3);
  const u16* ga0 = A + (size_t)(m0 + r0) * K + c8 * 8;
  const u16* ga1 = A + (size_t)(m0 + r1) * K + c8 * 8;
  const u16* gb0 = Bt + (size_t)(n0 + r0) * K + c8 * 8;
  const u16* gb1 = Bt + (size_t)(n0 + r1) * K + c8 * 8;
  u16* la0 = &As[tid * 8];
  u16* la1 = &As[(tid + 256) * 8];
  u16* lb0 = &Bs[tid * 8];
  u16* lb1 = &Bs[(tid + 256) * 8];

  int aoff[4], boff[4];
#pragma unroll
  for (int i = 0; i < 4; ++i) {
    int ra = wr * 64 + i * 16 + l16;
    aoff[i] = (ra * 4 + (quad ^ ((ra >> 1) & 3))) * 8;
    int rb = wc * 64 + i * 16 + l16;
    boff[i] = (rb * 4 + (quad ^ ((rb >> 1) & 3))) * 8;
  }

  const int nIter = K >> 5;
  for (int kt = 0; kt < nIter; ++kt) {
    __syncthreads();
    const int kk = kt << 5;
    GLOAD_LDS16(ga0 + kk, la0);
    GLOAD_LDS16(ga1 + kk, la1);
    GLOAD_LDS16(gb0 + kk, lb0);
    GLOAD_LDS16(gb1 + kk, lb1);
    __syncthreads();
    bf16x8 af[4], bfr[4];
#pragma unroll
    for (int i = 0; i < 4; ++i) af[i] = *(const bf16x8*)&As[aoff[i]];
#pragma unroll
    for (int j = 0; j < 4; ++j) bfr[j] = *(const bf16x8*)&Bs[boff[j]];
#pragma unroll
    for (int i = 0; i < 4; ++i)
#pragma unroll
      for (int j = 0; j < 4; ++j)
        acc[i][j] = MFMA16(af[i], bfr[j], acc[i][j]);
  }

  const int S = 2048, NH = 16;
#pragma unroll
  for (int i = 0; i < 4; ++i) {
    const int mb = m0 + wr * 64 + i * 16 + quad * 4;
#pragma unroll
    for (int j = 0; j < 4; ++j) {
      const int n = n0 + wc * 64 + j * 16 + l16;
      const float bv = bias[n];
      const int which = n >> 10;      // 0:Q 1:K 2:V (uniform per block)
      const int hn = n & 1023;
      const int h = hn >> 6, d = hn & 63;
      const int b = mb >> 11, s = mb & 2047;
      const int bh = b * NH + h;
      if (which == 2) {
        ushort4 pk;
        pk.x = f2bf(acc[i][j][0] + bv);
        pk.y = f2bf(acc[i][j][1] + bv);
        pk.z = f2bf(acc[i][j][2] + bv);
        pk.w = f2bf(acc[i][j][3] + bv);
        *(ushort4*)&vb[((size_t)bh * 64 + d) * S + s] = pk;  // V transposed
      } else {
        // Q pre-scaled by HD^-0.5 * log2(e): scores land in exp2 domain
        const float sc = (which == 0) ? 0.18033688f : 1.0f;
        u16* dst = (which == 0) ? qb : kb;
#pragma unroll
        for (int r = 0; r < 4; ++r)
          dst[((size_t)bh * S + s + r) * 64 + d] = f2bf((acc[i][j][r] + bv) * sc);
      }
    }
  }
}

// ---------------- GEMM 64x128: out = A @ Bt^T + bias (fp32 out) ----------
__global__ __launch_bounds__(256, 2) void gemm_out(
    const u16* __restrict__ A, const u16* __restrict__ Bt,
    const float* __restrict__ bias, float* __restrict__ outf,
    int M, int N, int K) {
  __shared__ u16 As[64 * 32];
  __shared__ u16 Bs[128 * 32];
  const int tid = threadIdx.x;
  const int m0 = blockIdx.x * 64;
  const int n0 = blockIdx.y * 128;
  const int lane = tid & 63, w = tid >> 6;
  const int quad = lane >> 4, l16 = lane & 15;
  const int wr = w >> 1, wc = w & 1;

  f32x4 acc[2][4] = {};

  const int r0 = tid >> 2, p0 = tid & 3;
  const int c8 = p0 ^ ((r0 >> 1) & 3);
  const u16* ga0 = A + (size_t)(m0 + r0) * K + c8 * 8;
  const u16* gb0 = Bt + (size_t)(n0 + r0) * K + c8 * 8;
  const u16* gb1 = Bt + (size_t)(n0 + r0 + 64) * K + c8 * 8;
  u16* la0 = &As[tid * 8];
  u16* lb0 = &Bs[tid * 8];
  u16* lb1 = &Bs[(tid + 256) * 8];

  int aoff[2], boff[4];
#pragma unroll
  for (int i = 0; i < 2; ++i) {
    int ra = wr * 32 + i * 16 + l16;
    aoff[i] = (ra * 4 + (quad ^ ((ra >> 1) & 3))) * 8;
  }
#pragma unroll
  for (int j = 0; j < 4; ++j) {
    int rb = wc * 64 + j * 16 + l16;
    boff[j] = (rb * 4 + (quad ^ ((rb >> 1) & 3))) * 8;
  }

  const int nIter = K >> 5;
  for (int kt = 0; kt < nIter; ++kt) {
    __syncthreads();
    const int kk = kt << 5;
    GLOAD_LDS16(ga0 + kk, la0);
    GLOAD_LDS16(gb0 + kk, lb0);
    GLOAD_LDS16(gb1 + kk, lb1);
    __syncthreads();
    bf16x8 af[2], bfr[4];
#pragma unroll
    for (int i = 0; i < 2; ++i) af[i] = *(const bf16x8*)&As[aoff[i]];
#pragma unroll
    for (int j = 0; j < 4; ++j) bfr[j] = *(const bf16x8*)&Bs[boff[j]];
#pragma unroll
    for (int i = 0; i < 2; ++i)
#pragma unroll
      for (int j = 0; j < 4; ++j)
        acc[i][j] = MFMA16(af[i], bfr[j], acc[i][j]);
  }

#pragma unroll
  for (int i = 0; i < 2; ++i) {
    const int mb = m0 + wr * 32 + i * 16 + quad * 4;
#pragma unroll
    for (int j = 0; j < 4; ++j) {
      const int n = n0 + wc * 64 + j * 16 + l16;
      const float bv = bias[n];
#pragma unroll
      for (int r = 0; r < 4; ++r)
        outf[(size_t)(mb + r) * N + n] = acc[i][j][r] + bv;
    }
  }
}

// ---------------- flash attention v13 (best measured: 43.9 us) -------------
// 128-key dbuf tiles, K+V both LDS (128B-row conflict-free layouts, 0
// measured conflicts), in-register ptrans, XCD-affine remap, bulk frag
// reads. MfmaUtil ~33% plateau confirmed across 6 structural variants
// (waves x2, P in-reg, V global, ILP hoist, PV pipeline, wk-split).
__global__ __launch_bounds__(256, 2) void attn_fa(
    const u16* __restrict__ qg, const u16* __restrict__ kg,
    const u16* __restrict__ vg, u16* __restrict__ o) {
  const int S = 2048;
  const int lin = blockIdx.x;
  const int xcd = lin & 7, chunk = lin >> 3;
  const int bh = xcd * 4 + (chunk & 3);
  const int qblk = chunk >> 2;
  const int b = bh >> 4, h = bh & 15;
  const int tid = threadIdx.x, w = tid >> 6, lane = tid & 63;
  const int quad = lane >> 4, l16 = lane & 15;

  __shared__ u16 Ks[2][8192];   // [128 key-rows][8 granules], ^(row&7) swizzle
  __shared__ u16 Vs[2][8192];   // [2 hh][64 d-rows][8 granules], ^(row&7)

  const int q0 = qblk * 128 + w * 32;
  const u16* qp = qg + ((size_t)bh * S + q0 + l16) * 64 + quad * 8;
  const bf16x8 qf00 = *(const bf16x8*)qp;
  const bf16x8 qf01 = *(const bf16x8*)(qp + 32);
  const bf16x8 qf10 = *(const bf16x8*)(qp + 1024);
  const bf16x8 qf11 = *(const bf16x8*)(qp + 1024 + 32);

  f32x4 accO0[4] = {}, accO1[4] = {};
  f32x4 accL0 = {}, accL1 = {};

  bf16x8 ones;
#pragma unroll
  for (int i = 0; i < 8; ++i) ones[i] = (__bf16)1.0f;

  const u16* kbase = kg + (size_t)bh * S * 64;
  const u16* vbase = vg + (size_t)bh * 64 * S;

  const int sr0 = tid >> 3, sp0 = tid & 7;
  const int c8s = sp0 ^ (sr0 & 7);
  const u16* kSrc = kbase + (size_t)sr0 * 64 + c8s * 8;
  const u16* vSrc = vbase + (size_t)sr0 * S + c8s * 8;

  const int kgA = (quad ^ (l16 & 7)) * 8;
  const int kgB = ((quad + 4) ^ (l16 & 7)) * 8;

#define STAGE_KV(KT, NB)                                                      \
  {                                                                           \
    _Pragma("unroll")                                                         \
    for (int seg = 0; seg < 4; ++seg) {                                       \
      GLOAD_LDS16(kSrc + (size_t)((KT) * 128 + seg * 32) * 64,                \
                  &Ks[NB][(seg * 256 + tid) * 8]);                            \
      GLOAD_LDS16(vSrc + (size_t)(seg & 1) * 32 * S + (KT) * 128 +            \
                      (seg >> 1) * 64,                                        \
                  &Vs[NB][(seg * 256 + tid) * 8]);                            \
    }                                                                         \
  }

  // preload tile 0 into buffer 0
  STAGE_KV(0, 0);

  for (int kt = 0; kt < 16; ++kt) {
    const int cur = kt & 1;
    __syncthreads();  // glds(kt) landed; buf[cur^1] reads of kt-1 complete
    const u16* Kc = Ks[cur];
    const u16* Vc = Vs[cur];

    // ---- ALL fragment reads upfront (32 x ds_read_b128) ----
    bf16x8 kf00[4], kf01[4], kf10[4], kf11[4];
    bf16x8 vf00[4], vf01[4], vf10[4], vf11[4];
#pragma unroll
    for (int ct = 0; ct < 4; ++ct) {
      const int rb0 = (ct * 16 + l16) * 64;
      const int rb1 = (64 + ct * 16 + l16) * 64;
      kf00[ct] = *(const bf16x8*)&Kc[rb0 + kgA];
      kf01[ct] = *(const bf16x8*)&Kc[rb0 + kgB];
      kf10[ct] = *(const bf16x8*)&Kc[rb1 + kgA];
      kf11[ct] = *(const bf16x8*)&Kc[rb1 + kgB];
      vf00[ct] = *(const bf16x8*)&Vc[rb0 + kgA];
      vf01[ct] = *(const bf16x8*)&Vc[rb0 + kgB];
      vf10[ct] = *(const bf16x8*)&Vc[4096 + rb0 + kgA];
      vf11[ct] = *(const bf16x8*)&Vc[4096 + rb0 + kgB];
    }

    // ---- prefetch next tile ----
    if (kt + 1 < 16) STAGE_KV(kt + 1, cur ^ 1);

    // ---- S^T = K Q^T, both halves ----
    f32x4 s0[4] = {}, s1[4] = {}, t0[4] = {}, t1[4] = {};
    __builtin_amdgcn_s_setprio(1);
#pragma unroll
    for (int ct = 0; ct < 4; ++ct) {
      s0[ct] = MFMA16(kf00[ct], qf00, s0[ct]);
      s0[ct] = MFMA16(kf01[ct], qf01, s0[ct]);
      s1[ct] = MFMA16(kf00[ct], qf10, s1[ct]);
      s1[ct] = MFMA16(kf01[ct], qf11, s1[ct]);
      t0[ct] = MFMA16(kf10[ct], qf00, t0[ct]);
      t0[ct] = MFMA16(kf11[ct], qf01, t0[ct]);
      t1[ct] = MFMA16(kf10[ct], qf10, t1[ct]);
      t1[ct] = MFMA16(kf11[ct], qf11, t1[ct]);
    }
    __builtin_amdgcn_s_setprio(0);

    // ---- P = exp2(s) ----
#pragma unroll
    for (int ct = 0; ct < 4; ++ct)
#pragma unroll
      for (int r = 0; r < 4; ++r) {
        s0[ct][r] = __builtin_amdgcn_exp2f(s0[ct][r]);
        s1[ct][r] = __builtin_amdgcn_exp2f(s1[ct][r]);
        t0[ct][r] = __builtin_amdgcn_exp2f(t0[ct][r]);
        t1[ct][r] = __builtin_amdgcn_exp2f(t1[ct][r]);
      }

    // ---- P^T fragments in-register ----
    bf16x8 pf00 = ptrans(s0[0], s0[1]);
    bf16x8 pf01 = ptrans(s0[2], s0[3]);
    bf16x8 pf10 = ptrans(s1[0], s1[1]);
    bf16x8 pf11 = ptrans(s1[2], s1[3]);
    bf16x8 pg00 = ptrans(t0[0], t0[1]);
    bf16x8 pg01 = ptrans(t0[2], t0[3]);
    bf16x8 pg10 = ptrans(t1[0], t1[1]);
    bf16x8 pg11 = ptrans(t1[2], t1[3]);

    // ---- row sums + O^T += V^T P^T, both halves ----
    __builtin_amdgcn_s_setprio(1);
    accL0 = MFMA16(ones, pf00, accL0);
    accL0 = MFMA16(ones, pf01, accL0);
    accL1 = MFMA16(ones, pf10, accL1);
    accL1 = MFMA16(ones, pf11, accL1);
    accL0 = MFMA16(ones, pg00, accL0);
    accL0 = MFMA16(ones, pg01, accL0);
    accL1 = MFMA16(ones, pg10, accL1);
    accL1 = MFMA16(ones, pg11, accL1);
#pragma unroll
    for (int ct = 0; ct < 4; ++ct) {
      accO0[ct] = MFMA16(vf00[ct], pf00, accO0[ct]);
      accO0[ct] = MFMA16(vf01[ct], pf01, accO0[ct]);
      accO1[ct] = MFMA16(vf00[ct], pf10, accO1[ct]);
      accO1[ct] = MFMA16(vf01[ct], pf11, accO1[ct]);
      accO0[ct] = MFMA16(vf10[ct], pg00, accO0[ct]);
      accO0[ct] = MFMA16(vf11[ct], pg01, accO0[ct]);
      accO1[ct] = MFMA16(vf10[ct], pg10, accO1[ct]);
      accO1[ct] = MFMA16(vf11[ct], pg11, accO1[ct]);
    }
    __builtin_amdgcn_s_setprio(0);
  }
#undef STAGE_KV

  const float inv0 = 1.f / accL0[0], inv1 = 1.f / accL1[0];

  const int s0r = q0 + l16, s1r = q0 + 16 + l16;
#pragma unroll
  for (int ct = 0; ct < 4; ++ct) {
    ushort4 pk;
    pk.x = f2bf(accO0[ct][0] * inv0);
    pk.y = f2bf(accO0[ct][1] * inv0);
    pk.z = f2bf(accO0[ct][2] * inv0);
    pk.w = f2bf(accO0[ct][3] * inv0);
    *(ushort4*)&o[(size_t)(b * S + s0r) * 1024 + h * 64 + ct * 16 + quad * 4] = pk;
    pk.x = f2bf(accO1[ct][0] * inv1);
    pk.y = f2bf(accO1[ct][1] * inv1);
    pk.z = f2bf(accO1[ct][2] * inv1);
    pk.w = f2bf(accO1[ct][3] * inv1);
    *(ushort4*)&o[(size_t)(b * S + s1r) * 1024 + h * 64 + ct * 16 + quad * 4] = pk;
  }
}

// ---------------- launch ----------------

extern "C" void kernel_launch(void* const* d_in, const int* in_sizes, int n_in,
                              void* d_out, int out_size, void* d_ws, size_t ws_size,
                              hipStream_t stream) {
  const float* x = (const float*)d_in[0];
  const float* w_qkv = (const float*)d_in[1];
  const float* b_qkv = (const float*)d_in[2];
  const float* w_out = (const float*)d_in[3];
  const float* b_out = (const float*)d_in[4];
  float* out = (float*)d_out;

  u16* xb = (u16*)d_ws;                 // [4096,1024]
  u16* wqT = xb + 4096 * 1024;          // [3072,1024]
  u16* woT = wqT + 3072 * 1024;         // [1024,1024]
  u16* qb = woT + 1024 * 1024;          // [32,2048,64] (pre-scaled)
  u16* kb = qb + 4194304;               // [32,2048,64]
  u16* vb = kb + 4194304;               // [32,64,2048]
  u16* ao = vb + 4194304;               // [4096,1024]

  prep<<<8192, 256, 0, stream>>>(x, w_qkv, w_out, xb, wqT, woT);
  gemm_qkv<<<dim3(32, 24), 256, 0, stream>>>(xb, wqT, b_qkv, qb, kb, vb,
                                             4096, 3072, 1024);
  attn_fa<<<512, 256, 0, stream>>>(qb, kb, vb, ao);
  gemm_out<<<dim3(64, 8), 256, 0, stream>>>(ao, woT, b_out, out,
                                            4096, 1024, 1024);
}